// Round 6
// baseline (18.277 us; speedup 1.0000x reference)
//
#include <hip/hip_runtime.h>

// Problem constants (B=128 states, n=16 qubits, D=2^16 amplitudes).
#define BATCH 128
#define DIM 65536
#define HALF 32768
#define TPB 1024                      // 16 waves
#define PAIRS_PER_BLOCK 16384         // half the pair range per block
#define ITERS 4                       // 16384 / 1024 = 16 pairs = 4 float4
#define MAGIC 0x5CA1AB1Eu

// Math: out[b] = cos^2(t)*sum(|a|^2-|b|^2) - 2 sin(t)*Re<a,b> + 2 sin(t)cos(t)*Im<a,b>
// where t = thetas[0], a = first half (bit0=0), b = second half (bit0=1).
// CNOT ladder commutes with Z_0; single-qubit gates on qubits 1..15 cancel.
//
// 256 blocks = 2 per batch element so ALL 256 CUs stream bytes (R5 used 128).
// Cross-block combine without an init node: block (b,0) release-stores its
// coefficient-applied partial + MAGIC flag into d_ws; block (b,1) spins
// (acquire, agent scope) until MAGIC, sums, writes out[b]. Poison 0xAAAAAAAA
// != MAGIC; stale values from earlier replays are bit-identical (deterministic
// kernel), so a stale MAGIC is harmless. Only c==1 blocks spin -> progress
// guaranteed under any scheduling.

#define LD4(p) (*reinterpret_cast<const float4*>(p))

__global__ __launch_bounds__(TPB) void qcirc_split(
    const float* __restrict__ re, const float* __restrict__ im,
    const float* __restrict__ thetas, float* __restrict__ out,
    float* __restrict__ ws_val, unsigned int* __restrict__ ws_flag)
{
    const int bid = blockIdx.x;
    const int b = bid >> 1;           // batch element
    const int c = bid & 1;            // which half of the pair range
    const int t = threadIdx.x;

    const size_t row = (size_t)b * DIM;
    const int poff = c * PAIRS_PER_BLOCK;
    const float* ra_p = re + row + poff;          // re, bit0 = 0 half
    const float* rb_p = re + row + HALF + poff;   // re, bit0 = 1 half
    const float* ia_p = im + row + poff;          // im, bit0 = 0 half
    const float* ib_p = im + row + HALF + poff;   // im, bit0 = 1 half

    float diff0 = 0.f, diff1 = 0.f;
    float dre0  = 0.f, dre1  = 0.f;
    float dim0  = 0.f, dim1  = 0.f;

    // 2-deep register pipeline
    int r = t * 4;
    float4 cra = LD4(ra_p + r), cia = LD4(ia_p + r);
    float4 crb = LD4(rb_p + r), cib = LD4(ib_p + r);

    #pragma unroll
    for (int i = 0; i < ITERS; ++i) {
        float4 nra, nia, nrb, nib;
        if (i < ITERS - 1) {
            const int rn = ((i + 1) * TPB + t) * 4;
            nra = LD4(ra_p + rn); nia = LD4(ia_p + rn);
            nrb = LD4(rb_p + rn); nib = LD4(ib_p + rn);
        }

        if ((i & 1) == 0) {
            diff0 += cra.x*cra.x + cia.x*cia.x - crb.x*crb.x - cib.x*cib.x;
            diff0 += cra.y*cra.y + cia.y*cia.y - crb.y*crb.y - cib.y*cib.y;
            diff0 += cra.z*cra.z + cia.z*cia.z - crb.z*crb.z - cib.z*cib.z;
            diff0 += cra.w*cra.w + cia.w*cia.w - crb.w*crb.w - cib.w*cib.w;
            dre0  += cra.x*crb.x + cia.x*cib.x + cra.y*crb.y + cia.y*cib.y;
            dre0  += cra.z*crb.z + cia.z*cib.z + cra.w*crb.w + cia.w*cib.w;
            dim0  += cra.x*cib.x - cia.x*crb.x + cra.y*cib.y - cia.y*crb.y;
            dim0  += cra.z*cib.z - cia.z*crb.z + cra.w*cib.w - cia.w*crb.w;
        } else {
            diff1 += cra.x*cra.x + cia.x*cia.x - crb.x*crb.x - cib.x*cib.x;
            diff1 += cra.y*cra.y + cia.y*cia.y - crb.y*crb.y - cib.y*cib.y;
            diff1 += cra.z*cra.z + cia.z*cia.z - crb.z*crb.z - cib.z*cib.z;
            diff1 += cra.w*cra.w + cia.w*cia.w - crb.w*crb.w - cib.w*cib.w;
            dre1  += cra.x*crb.x + cia.x*cib.x + cra.y*crb.y + cia.y*cib.y;
            dre1  += cra.z*crb.z + cia.z*cib.z + cra.w*crb.w + cia.w*cib.w;
            dim1  += cra.x*cib.x - cia.x*crb.x + cra.y*cib.y - cia.y*crb.y;
            dim1  += cra.z*cib.z - cia.z*crb.z + cra.w*cib.w - cia.w*crb.w;
        }

        if (i < ITERS - 1) { cra = nra; cia = nia; crb = nrb; cib = nib; }
    }

    float diff = diff0 + diff1;
    float dre  = dre0 + dre1;
    float dim_ = dim0 + dim1;

    // wave64 butterfly reduce
    #pragma unroll
    for (int off = 32; off > 0; off >>= 1) {
        diff += __shfl_down(diff, off);
        dre  += __shfl_down(dre,  off);
        dim_ += __shfl_down(dim_, off);
    }

    __shared__ float sdata[3][TPB / 64];             // 16 waves
    const int wave = t >> 6, lane = t & 63;
    if (lane == 0) {
        sdata[0][wave] = diff;
        sdata[1][wave] = dre;
        sdata[2][wave] = dim_;
    }
    __syncthreads();

    if (t == 0) {
        float d = 0.f, rr = 0.f, ii = 0.f;
        #pragma unroll
        for (int w = 0; w < TPB / 64; ++w) {
            d += sdata[0][w]; rr += sdata[1][w]; ii += sdata[2][w];
        }
        const float theta = thetas[0];
        const float ct = __cosf(theta);
        const float st = __sinf(theta);
        const float val = ct * ct * d - 2.f * st * rr + 2.f * st * ct * ii;

        if (c == 0) {
            // publish partial for partner block (agent scope: cross-XCD)
            __hip_atomic_store(&ws_val[b], val,
                               __ATOMIC_RELAXED, __HIP_MEMORY_SCOPE_AGENT);
            __hip_atomic_store(&ws_flag[b], MAGIC,
                               __ATOMIC_RELEASE, __HIP_MEMORY_SCOPE_AGENT);
        } else {
            while (__hip_atomic_load(&ws_flag[b], __ATOMIC_ACQUIRE,
                                     __HIP_MEMORY_SCOPE_AGENT) != MAGIC) {
                __builtin_amdgcn_s_sleep(1);
            }
            const float other = __hip_atomic_load(&ws_val[b], __ATOMIC_RELAXED,
                                                  __HIP_MEMORY_SCOPE_AGENT);
            out[b] = val + other;
        }
    }
}

extern "C" void kernel_launch(void* const* d_in, const int* in_sizes, int n_in,
                              void* d_out, int out_size, void* d_ws, size_t ws_size,
                              hipStream_t stream) {
    const float* re     = (const float*)d_in[0];
    const float* im     = (const float*)d_in[1];
    const float* thetas = (const float*)d_in[2];
    float* out = (float*)d_out;
    float* ws_val = (float*)d_ws;                       // 128 floats
    unsigned int* ws_flag = (unsigned int*)d_ws + BATCH; // 128 uints

    qcirc_split<<<2 * BATCH, TPB, 0, stream>>>(re, im, thetas, out, ws_val, ws_flag);
}

// Round 7
// 17.806 us; speedup vs baseline: 1.0265x; 1.0265x over previous
//
#include <hip/hip_runtime.h>

// Problem constants (B=128 states, n=16 qubits, D=2^16 amplitudes).
#define BATCH 128
#define DIM 65536
#define HALF 32768
#define TPB 1024                     // 16 waves; one block per batch element
#define ITERS 8                      // 32768 pairs / 1024 threads = 32 = 8 float4

// Math: out[b] = cos^2(t)*sum(|a|^2-|b|^2) - 2 sin(t)*Re<a,b> + 2 sin(t)cos(t)*Im<a,b>
// where t = thetas[0], a = first half (bit0=0), b = second half (bit0=1).
// CNOT ladder commutes with Z_0; single-qubit gates on qubits 1..15 cancel.
//
// Final topology (R0-R6 search): ONE kernel node, one block per batch element,
// block-local reduction only. Measured dead ends: tail kernel (+~2-5us, R1),
// memset+atomic node (+7us, R2), cooperative grid.sync (+110us, R3),
// 256-block flag handshake (+2.6us, R6). 2-deep register pipeline holds
// 4 float4/thread in flight (8.4 MB device-wide > 5.7 MB BW-latency product),
// which brought exec to ~10.7us = 6.27 TB/s ~= m13's 6.29 TB/s achievable.

#define LD4(p) (*reinterpret_cast<const float4*>(p))

__global__ __launch_bounds__(TPB, 4) void qcirc_block(
    const float* __restrict__ re, const float* __restrict__ im,
    const float* __restrict__ thetas, float* __restrict__ out)
{
    const int b = blockIdx.x;
    const int t = threadIdx.x;

    const float* ra_p = re + (size_t)b * DIM;        // re, bit0 = 0 half
    const float* rb_p = ra_p + HALF;                 // re, bit0 = 1 half
    const float* ia_p = im + (size_t)b * DIM;        // im, bit0 = 0 half
    const float* ib_p = ia_p + HALF;                 // im, bit0 = 1 half

    // two accumulator sets to break the serial FMA chain
    float diff0 = 0.f, diff1 = 0.f;
    float dre0  = 0.f, dre1  = 0.f;
    float dim0  = 0.f, dim1  = 0.f;

    // prologue: load iteration 0
    int r = t * 4;
    float4 cra = LD4(ra_p + r), cia = LD4(ia_p + r);
    float4 crb = LD4(rb_p + r), cib = LD4(ib_p + r);

    #pragma unroll
    for (int i = 0; i < ITERS; ++i) {
        float4 nra, nia, nrb, nib;
        if (i < ITERS - 1) {
            const int rn = ((i + 1) * TPB + t) * 4;  // coalesced float4
            nra = LD4(ra_p + rn); nia = LD4(ia_p + rn);
            nrb = LD4(rb_p + rn); nib = LD4(ib_p + rn);
        }

        if ((i & 1) == 0) {
            diff0 += cra.x*cra.x + cia.x*cia.x - crb.x*crb.x - cib.x*cib.x;
            diff0 += cra.y*cra.y + cia.y*cia.y - crb.y*crb.y - cib.y*cib.y;
            diff0 += cra.z*cra.z + cia.z*cia.z - crb.z*crb.z - cib.z*cib.z;
            diff0 += cra.w*cra.w + cia.w*cia.w - crb.w*crb.w - cib.w*cib.w;
            dre0  += cra.x*crb.x + cia.x*cib.x + cra.y*crb.y + cia.y*cib.y;
            dre0  += cra.z*crb.z + cia.z*cib.z + cra.w*crb.w + cia.w*cib.w;
            dim0  += cra.x*cib.x - cia.x*crb.x + cra.y*cib.y - cia.y*crb.y;
            dim0  += cra.z*cib.z - cia.z*crb.z + cra.w*cib.w - cia.w*crb.w;
        } else {
            diff1 += cra.x*cra.x + cia.x*cia.x - crb.x*crb.x - cib.x*cib.x;
            diff1 += cra.y*cra.y + cia.y*cia.y - crb.y*crb.y - cib.y*cib.y;
            diff1 += cra.z*cra.z + cia.z*cia.z - crb.z*crb.z - cib.z*cib.z;
            diff1 += cra.w*cra.w + cia.w*cia.w - crb.w*crb.w - cib.w*cib.w;
            dre1  += cra.x*crb.x + cia.x*cib.x + cra.y*crb.y + cia.y*cib.y;
            dre1  += cra.z*crb.z + cia.z*cib.z + cra.w*crb.w + cia.w*cib.w;
            dim1  += cra.x*cib.x - cia.x*crb.x + cra.y*cib.y - cia.y*crb.y;
            dim1  += cra.z*cib.z - cia.z*crb.z + cra.w*cib.w - cia.w*crb.w;
        }

        if (i < ITERS - 1) { cra = nra; cia = nia; crb = nrb; cib = nib; }
    }

    float diff = diff0 + diff1;
    float dre  = dre0 + dre1;
    float dim_ = dim0 + dim1;

    // wave64 butterfly reduce
    #pragma unroll
    for (int off = 32; off > 0; off >>= 1) {
        diff += __shfl_down(diff, off);
        dre  += __shfl_down(dre,  off);
        dim_ += __shfl_down(dim_, off);
    }

    __shared__ float sdata[3][TPB / 64];             // 16 waves
    const int wave = t >> 6, lane = t & 63;
    if (lane == 0) {
        sdata[0][wave] = diff;
        sdata[1][wave] = dre;
        sdata[2][wave] = dim_;
    }
    __syncthreads();

    if (t < 16) {
        float d = sdata[0][t], rr = sdata[1][t], ii = sdata[2][t];
        #pragma unroll
        for (int off = 8; off > 0; off >>= 1) {
            d  += __shfl_down(d,  off);
            rr += __shfl_down(rr, off);
            ii += __shfl_down(ii, off);
        }
        if (t == 0) {
            const float theta = thetas[0];
            const float ct = __cosf(theta);
            const float st = __sinf(theta);
            out[b] = ct * ct * d - 2.f * st * rr + 2.f * st * ct * ii;
        }
    }
}

extern "C" void kernel_launch(void* const* d_in, const int* in_sizes, int n_in,
                              void* d_out, int out_size, void* d_ws, size_t ws_size,
                              hipStream_t stream) {
    const float* re     = (const float*)d_in[0];
    const float* im     = (const float*)d_in[1];
    const float* thetas = (const float*)d_in[2];
    float* out = (float*)d_out;

    qcirc_block<<<BATCH, TPB, 0, stream>>>(re, im, thetas, out);
}